// Round 16
// baseline (2489.759 us; speedup 1.0000x reference)
//
#include <hip/hip_runtime.h>

#define N_NODES 100000
#define IN_CH   256
#define HID_D   64
#define NCLS    6
#define NE      1600000
#define WB      48          // padded bucket width (Poisson(16) max deg ~42; ovf guard)
#define OVF_CAP 4096
#define NPART   8           // = #XCDs
#define PSZ     (N_NODES / NPART)   // 12500
#define QCAP    204800      // per-partition queue cap (~11 sigma over 200k mean)

typedef unsigned short u16;
typedef unsigned int   u32;
typedef unsigned long long u64;
typedef __attribute__((ext_vector_type(8))) short bf16x8;
typedef __attribute__((ext_vector_type(4))) float f32x4;
typedef __attribute__((ext_vector_type(2))) int   i32x2;

// ws layout (bytes)
#define OFF_CNT   0u                    // 100000*4 = 400000
#define OFF_OVFC  400000u               // 4
#define OFF_QCNT  400032u               // 8*4
#define OFF_OVF   400128u               // 4096*2*4 = 32768 -> 432896
#define OFF_COL   433152u               // 100000*48*4 = 19,200,000 -> 19,633,152
#define OFF_WT    19633152u             // 25600 u16 fragment tables -> 19,684,352
#define OFF_G     19684480u             // 12,800,000 (bf16) -> 32,484,480
#define OFF_H     32484480u             // 12,800,000 (bf16) -> 45,284,480
#define OFF_QBUF  OFF_G                 // queues alias G (+ head of H); dead before gemm1
// fragment-table element offsets (u16 units)
#define WT_W1 0
#define WT_W2 16384
#define WT_WP 20480
#define WT_WC 24576
#define WT_TOT 25600
#define Z_OFF 600000u                   // d_out f32: logits [0,600000), z rest

__device__ __forceinline__ u16 f2bf(float f) {
    u32 u = __float_as_uint(f);
    return (u16)((u + 0x7fffu + ((u >> 16) & 1u)) >> 16);   // RNE
}
__device__ __forceinline__ float bf2f(u16 h) {
    return __uint_as_float(((u32)h) << 16);
}

// ---- one-time weight -> fragment-ordered bf16 tables ----
// R15 bug: WC table is [kk:2][l:64][j:8] (kk = i>>9), NOT the [kk][t][l][j]
// layout of W1/W2/Wp (kk = i>>11). Decode per-table now.
__global__ __launch_bounds__(256) void k_wprep(const float* __restrict__ W1,
                                               const float* __restrict__ W2,
                                               const float* __restrict__ Wp,
                                               const float* __restrict__ Wc,
                                               u16* __restrict__ wt) {
    int m = blockIdx.x * 256 + threadIdx.x;       // grid exact: 25600/256 = 100
    if (m >= WT_TOT) return;
    float v;
    if (m >= WT_WC) {                             // Wc: [2][64][8], c = l&15
        int i = m - WT_WC;
        int j = i & 7, l = (i >> 3) & 63, kk = i >> 9;
        int k = kk * 32 + (l >> 4) * 8 + j;
        int c = l & 15;
        v = (c < NCLS) ? Wc[k * NCLS + c] : 0.f;
    } else {                                      // W1/W2/Wp: [KK][4][64][8]
        const float* src; int i;
        if      (m < WT_W2) { src = W1; i = m - WT_W1; }
        else if (m < WT_WP) { src = W2; i = m - WT_W2; }
        else                { src = Wp; i = m - WT_WP; }
        int j = i & 7, l = (i >> 3) & 63, t = (i >> 9) & 3, kk = i >> 11;
        int k = kk * 32 + (l >> 4) * 8 + j;
        int c = t * 16 + (l & 15);
        v = src[k * 64 + c];
    }
    wt[m] = f2bf(v);
}

// ---- phase 1: ballot-compacted edge partition into 8 dst-range queues ----
__global__ __launch_bounds__(256) void k_part(const int* __restrict__ ei,
                                              int* __restrict__ qcnt,
                                              int2* __restrict__ qbuf) {
    const int tid  = threadIdx.x;
    const int lane = tid & 63;
    const int e0 = blockIdx.x * 512 + tid * 2;    // grid exact: NE/512 = 3125
    i32x2 s2 = __builtin_nontemporal_load((const i32x2*)(ei + e0));
    i32x2 d2 = __builtin_nontemporal_load((const i32x2*)(ei + NE + e0));
#pragma unroll
    for (int j = 0; j < 2; ++j) {
        int s = s2[j];
        int d = d2[j];
        int p = (u32)d < (u32)N_NODES ? d / PSZ : 0;
#pragma unroll
        for (int q = 0; q < NPART; ++q) {
            u64 m = __ballot(p == q);
            if (m == 0ull) continue;              // wave-uniform
            int nq = __popcll(m);
            int leader = __ffsll((long long)m) - 1;
            int base = 0;
            if (lane == leader) base = atomicAdd(&qcnt[q], nq);
            base = __shfl(base, leader);
            if (p == q) {
                int pos = __popcll(m & ((1ull << lane) - 1ull));
                if (base + pos < QCAP)
                    qbuf[(size_t)q * QCAP + base + pos] = make_int2(s, d);
            }
        }
    }
}

// ---- phase 2: per-XCD bucket fill from the partition's own queue ----
__global__ __launch_bounds__(256) void k_fill2(const int* __restrict__ qb,
                                               const int* __restrict__ qcnt,
                                               int* __restrict__ cnt,
                                               int* __restrict__ col,
                                               int* __restrict__ ovfc,
                                               int* __restrict__ ovf) {
    const int part = blockIdx.x & (NPART - 1);    // matches round-robin XCD
    const int n = min(qcnt[part], QCAP);
    const int* q = qb + (size_t)part * QCAP * 2;
    const int stride = (gridDim.x >> 3) * 256;
    for (int i = (blockIdx.x >> 3) * 256 + threadIdx.x; i < n; i += stride) {
        i32x2 e = __builtin_nontemporal_load((const i32x2*)(q + 2 * i));
        int s = e[0], d = e[1];
        if ((u32)s >= (u32)N_NODES || (u32)d >= (u32)N_NODES) continue;
        int p = atomicAdd(&cnt[d], 1);
        if (p < WB) {
            col[(size_t)d * WB + p] = s;
        } else {
            int k = atomicAdd(ovfc, 1);
            if (k < OVF_CAP) { ovf[2 * k] = s; ovf[2 * k + 1] = d; }
        }
    }
}

// ---- G(bf16) = dinv .* (A @ W); staging from pre-built fragment table ----
template <int KDIM, bool ABF16>
__global__ __launch_bounds__(256) void k_gemm(const void* __restrict__ A,
                                              const u16* __restrict__ wt,
                                              const int* __restrict__ cnt,
                                              u16* __restrict__ G) {
    constexpr int KK = KDIM / 32;
    __shared__ __align__(16) u16 sB[KK * 2048];

    for (int idx = threadIdx.x * 8; idx < KK * 2048; idx += 2048)
        *(bf16x8*)&sB[idx] = *(const bf16x8*)&wt[idx];   // linear coalesced
    __syncthreads();

    const int lane = threadIdx.x & 63;
    const int wv   = threadIdx.x >> 6;
    const int row0 = blockIdx.x * 64 + wv * 16;
    const int g4   = lane >> 4;
    const int r16  = lane & 15;

    int arow = row0 + r16;
    int arow_c = arow < N_NODES ? arow : 0;

    f32x4 acc[4] = {{0,0,0,0},{0,0,0,0},{0,0,0,0},{0,0,0,0}};

#pragma unroll
    for (int kk = 0; kk < KK; ++kk) {
        bf16x8 a;
        if (ABF16) {
            a = *(const bf16x8*)((const u16*)A + (size_t)arow_c * KDIM + kk * 32 + g4 * 8);
        } else {
            const float* ap = (const float*)A + (size_t)arow_c * KDIM + kk * 32 + g4 * 8;
            float4 f0 = *(const float4*)ap;
            float4 f1 = *(const float4*)(ap + 4);
            a[0] = (short)f2bf(f0.x); a[1] = (short)f2bf(f0.y);
            a[2] = (short)f2bf(f0.z); a[3] = (short)f2bf(f0.w);
            a[4] = (short)f2bf(f1.x); a[5] = (short)f2bf(f1.y);
            a[6] = (short)f2bf(f1.z); a[7] = (short)f2bf(f1.w);
        }
#pragma unroll
        for (int t = 0; t < 4; ++t) {
            bf16x8 b = *(const bf16x8*)&sB[((kk * 4 + t) * 64 + lane) * 8];
            acc[t] = __builtin_amdgcn_mfma_f32_16x16x32_bf16(a, b, acc[t], 0, 0, 0);
        }
    }

#pragma unroll
    for (int r = 0; r < 4; ++r) {
        int row = row0 + g4 * 4 + r;
        if (row < N_NODES) {
            float dinv = rsqrtf((float)(cnt[row] + 1));
#pragma unroll
            for (int t = 0; t < 4; ++t)
                G[(size_t)row * 64 + t * 16 + r16] = f2bf(acc[t][r] * dinv);
        }
    }
}

// ---- Hout(bf16) = relu(dinv[i]*(g[i] + sum_{e:dst=i} g[src_e]) + bias) ----
__global__ __launch_bounds__(256) void k_agg(const u16* __restrict__ G,
                                             const int* __restrict__ col,
                                             const int* __restrict__ cnt,
                                             const int* __restrict__ ovfc,
                                             const int* __restrict__ ovf,
                                             const float* __restrict__ bias,
                                             u16* __restrict__ Hout) {
    int node = blockIdx.x * 4 + (threadIdx.x >> 6);   // grid exact: N/4
    int lane = threadIdx.x & 63;

    int deg = cnt[node];
    int m = min(deg, WB);
    int mycol = (lane < WB) ? col[(size_t)node * WB + lane] : 0;

    float acc = bf2f(G[(size_t)node * 64 + lane]);    // self loop

    int e = 0;
    for (; e + 4 <= m; e += 4) {
        int c0 = __shfl(mycol, e + 0), c1 = __shfl(mycol, e + 1);
        int c2 = __shfl(mycol, e + 2), c3 = __shfl(mycol, e + 3);
        float v0 = bf2f(G[(size_t)c0 * 64 + lane]);
        float v1 = bf2f(G[(size_t)c1 * 64 + lane]);
        float v2 = bf2f(G[(size_t)c2 * 64 + lane]);
        float v3 = bf2f(G[(size_t)c3 * 64 + lane]);
        acc += v0; acc += v1; acc += v2; acc += v3;
    }
    for (; e < m; ++e) {
        int c = __shfl(mycol, e);
        acc += bf2f(G[(size_t)c * 64 + lane]);
    }

    int no = *ovfc;
    if (no > 0) {                        // ~never taken (deg > 48)
        no = min(no, OVF_CAP);
        for (int j = 0; j < no; ++j)
            if (ovf[2 * j + 1] == node)
                acc += bf2f(G[(size_t)ovf[2 * j] * 64 + lane]);
    }

    float dinv = rsqrtf((float)(deg + 1));
    float v = fmaxf(acc * dinv + bias[lane], 0.f);
    Hout[(size_t)node * 64 + lane] = f2bf(v);
}

// ---- z = relu(H@Wp+bp) -> out f32 [Z_OFF..]; logits = z@Wc+bc -> out f32 ----
__global__ __launch_bounds__(256) void k_mlp(const u16* __restrict__ H,
                                             const u16* __restrict__ wt,
                                             const float* __restrict__ bp,
                                             const float* __restrict__ bc,
                                             float* __restrict__ out) {
    __shared__ __align__(16) u16 sP[2 * 2048];
    __shared__ __align__(16) u16 sC[1024];
    __shared__ __align__(16) u16 zt[4][16][72];

    for (int idx = threadIdx.x * 8; idx < 4096; idx += 2048)
        *(bf16x8*)&sP[idx] = *(const bf16x8*)&wt[WT_WP + idx];
    {
        int idx = threadIdx.x * 8;
        if (idx < 1024)
            *(bf16x8*)&sC[idx] = *(const bf16x8*)&wt[WT_WC + idx];
    }
    __syncthreads();

    const int lane = threadIdx.x & 63;
    const int wv   = threadIdx.x >> 6;
    const int row0 = blockIdx.x * 64 + wv * 16;
    const int g4   = lane >> 4;
    const int r16  = lane & 15;

    int arow = row0 + r16;
    int arow_c = arow < N_NODES ? arow : (N_NODES - 1);

    f32x4 zac[4] = {{0,0,0,0},{0,0,0,0},{0,0,0,0},{0,0,0,0}};
#pragma unroll
    for (int kk = 0; kk < 2; ++kk) {
        bf16x8 a = *(const bf16x8*)((const u16*)H + (size_t)arow_c * 64 + kk * 32 + g4 * 8);
#pragma unroll
        for (int t = 0; t < 4; ++t) {
            bf16x8 b = *(const bf16x8*)&sP[((kk * 4 + t) * 64 + lane) * 8];
            zac[t] = __builtin_amdgcn_mfma_f32_16x16x32_bf16(a, b, zac[t], 0, 0, 0);
        }
    }

#pragma unroll
    for (int r = 0; r < 4; ++r) {
        int row = row0 + g4 * 4 + r;
#pragma unroll
        for (int t = 0; t < 4; ++t) {
            float v = zac[t][r] + bp[t * 16 + r16];
            v = fmaxf(v, 0.f);
            zt[wv][g4 * 4 + r][t * 16 + r16] = f2bf(v);
            if (row < N_NODES)
                out[(size_t)Z_OFF + (size_t)row * 64 + t * 16 + r16] = v;
        }
    }
    __syncthreads();

    f32x4 lac = {0, 0, 0, 0};
#pragma unroll
    for (int kk = 0; kk < 2; ++kk) {
        bf16x8 a = *(const bf16x8*)&zt[wv][r16][kk * 32 + g4 * 8];
        bf16x8 b = *(const bf16x8*)&sC[(kk * 64 + lane) * 8];
        lac = __builtin_amdgcn_mfma_f32_16x16x32_bf16(a, b, lac, 0, 0, 0);
    }
#pragma unroll
    for (int r = 0; r < 4; ++r) {
        int row = row0 + g4 * 4 + r;
        if (row < N_NODES && r16 < NCLS)
            out[(size_t)row * NCLS + r16] = lac[r] + bc[r16];
    }
}

extern "C" void kernel_launch(void* const* d_in, const int* in_sizes, int n_in,
                              void* d_out, int out_size, void* d_ws, size_t ws_size,
                              hipStream_t stream) {
    const float* x  = (const float*)d_in[0];
    const int*   ei = (const int*)d_in[1];
    const float* W1 = (const float*)d_in[2];
    const float* b1 = (const float*)d_in[3];
    const float* W2 = (const float*)d_in[4];
    const float* b2 = (const float*)d_in[5];
    const float* Wp = (const float*)d_in[6];
    const float* bp = (const float*)d_in[7];
    const float* Wc = (const float*)d_in[8];
    const float* bc = (const float*)d_in[9];
    float* out = (float*)d_out;

    char* ws   = (char*)d_ws;
    int*  cnt  = (int*)(ws + OFF_CNT);
    int*  ovfc = (int*)(ws + OFF_OVFC);
    int*  qcnt = (int*)(ws + OFF_QCNT);
    int*  ovf  = (int*)(ws + OFF_OVF);
    int*  col  = (int*)(ws + OFF_COL);
    u16*  wt   = (u16*)(ws + OFF_WT);
    int2* qbuf = (int2*)(ws + OFF_QBUF);
    u16*  g    = (u16*)(ws + OFF_G);
    u16*  h    = (u16*)(ws + OFF_H);

    const int GB = (N_NODES + 63) / 64;   // 1563

    (void)hipMemsetAsync(ws, 0, OFF_OVF, stream);      // cnt + ovfc + qcnt
    k_wprep<<<WT_TOT / 256, 256, 0, stream>>>(W1, W2, Wp, Wc, wt);
    k_part<<<NE / 512, 256, 0, stream>>>(ei, qcnt, qbuf);
    k_fill2<<<128 * NPART, 256, 0, stream>>>((const int*)qbuf, qcnt, cnt, col, ovfc, ovf);
    k_gemm<IN_CH, false><<<GB, 256, 0, stream>>>(x, wt + WT_W1, cnt, g);
    k_agg<<<N_NODES / 4, 256, 0, stream>>>(g, col, cnt, ovfc, ovf, b1, h);
    k_gemm<HID_D, true><<<GB, 256, 0, stream>>>(h, wt + WT_W2, cnt, g);
    k_agg<<<N_NODES / 4, 256, 0, stream>>>(g, col, cnt, ovfc, ovf, b2, h);
    k_mlp<<<GB, 256, 0, stream>>>(h, wt, bp, bc, out);
}

// Round 17
// 222.748 us; speedup vs baseline: 11.1775x; 11.1775x over previous
//
#include <hip/hip_runtime.h>

#define N_NODES 100000
#define IN_CH   256
#define HID_D   64
#define NCLS    6
#define NE      1600000
#define WB      48          // padded bucket width (Poisson(16) max deg ~42; ovf guard)
#define OVF_CAP 4096
#define NPART   8           // = #XCDs
#define PSZ     (N_NODES / NPART)   // 12500

typedef unsigned short u16;
typedef unsigned int   u32;
typedef __attribute__((ext_vector_type(8))) short bf16x8;
typedef __attribute__((ext_vector_type(4))) float f32x4;
typedef __attribute__((ext_vector_type(2))) int   i32x2;

// ws layout (bytes)
#define OFF_CNT   0u                    // 100000*4 = 400000
#define OFF_OVFC  400000u               // 4
#define OFF_OVF   400128u               // 4096*2*4 = 32768 -> 432896
#define OFF_COL   433152u               // 100000*48*4 = 19,200,000 -> 19,633,152
#define OFF_WT    19633152u             // 25600 u16 fragment tables -> 19,684,352
#define OFF_G     19684480u             // 12,800,000 (bf16) -> 32,484,480
#define OFF_H     32484480u             // 12,800,000 (bf16) -> 45,284,480
// fragment-table element offsets (u16 units)
#define WT_W1 0
#define WT_W2 16384
#define WT_WP 20480
#define WT_WC 24576
#define WT_TOT 25600
#define Z_OFF 600000u                   // d_out f32: logits [0,600000), z rest

__device__ __forceinline__ u16 f2bf(float f) {
    u32 u = __float_as_uint(f);
    return (u16)((u + 0x7fffu + ((u >> 16) & 1u)) >> 16);   // RNE
}
__device__ __forceinline__ float bf2f(u16 h) {
    return __uint_as_float(((u32)h) << 16);
}

// ---- one-time weight -> fragment-ordered bf16 tables (R16-validated) ----
__global__ __launch_bounds__(256) void k_wprep(const float* __restrict__ W1,
                                               const float* __restrict__ W2,
                                               const float* __restrict__ Wp,
                                               const float* __restrict__ Wc,
                                               u16* __restrict__ wt) {
    int m = blockIdx.x * 256 + threadIdx.x;       // grid exact: 25600/256 = 100
    if (m >= WT_TOT) return;
    float v;
    if (m >= WT_WC) {                             // Wc: [2][64][8], c = l&15
        int i = m - WT_WC;
        int j = i & 7, l = (i >> 3) & 63, kk = i >> 9;
        int k = kk * 32 + (l >> 4) * 8 + j;
        int c = l & 15;
        v = (c < NCLS) ? Wc[k * NCLS + c] : 0.f;
    } else {                                      // W1/W2/Wp: [KK][4][64][8]
        const float* src; int i;
        if      (m < WT_W2) { src = W1; i = m - WT_W1; }
        else if (m < WT_WP) { src = W2; i = m - WT_W2; }
        else                { src = Wp; i = m - WT_WP; }
        int j = i & 7, l = (i >> 3) & 63, t = (i >> 9) & 3, kk = i >> 11;
        int k = kk * 32 + (l >> 4) * 8 + j;
        int c = t * 16 + (l & 15);
        v = src[k * 64 + c];
    }
    wt[m] = f2bf(v);
}

// ---- XCD-partitioned single-phase bucket fill (R12 version, proven 74us) ----
// R16 lesson: ballot two-phase k_part serialized ~200K atomics on ONE cache
// line holding all 8 queue counters -> 2271us. Single-phase spreads its 1.6M
// cnt atomics over 100K addresses (no per-address hotspot).
__global__ __launch_bounds__(256) void k_fill(const int* __restrict__ ei,
                                              int* __restrict__ cnt,
                                              int* __restrict__ col,
                                              int* __restrict__ ovfc,
                                              int* __restrict__ ovf) {
    const int part = blockIdx.x & (NPART - 1);
    const int lo = part * PSZ;
    const int hi = lo + PSZ;
    const int e0 = (blockIdx.x >> 3) * 512 + threadIdx.x * 2;   // grid: (NE/512)*8
    i32x2 s2 = __builtin_nontemporal_load((const i32x2*)(ei + e0));
    i32x2 d2 = __builtin_nontemporal_load((const i32x2*)(ei + NE + e0));
#pragma unroll
    for (int j = 0; j < 2; ++j) {
        int s = s2[j];
        int d = d2[j];
        if (d < lo || d >= hi) continue;
        if ((u32)s >= (u32)N_NODES) continue;
        int p = atomicAdd(&cnt[d], 1);
        if (p < WB) {
            col[(size_t)d * WB + p] = s;
        } else {
            int k = atomicAdd(ovfc, 1);
            if (k < OVF_CAP) { ovf[2 * k] = s; ovf[2 * k + 1] = d; }
        }
    }
}

// ---- G(bf16) = dinv .* (A @ W); staging from pre-built fragment table ----
template <int KDIM, bool ABF16>
__global__ __launch_bounds__(256) void k_gemm(const void* __restrict__ A,
                                              const u16* __restrict__ wt,
                                              const int* __restrict__ cnt,
                                              u16* __restrict__ G) {
    constexpr int KK = KDIM / 32;
    __shared__ __align__(16) u16 sB[KK * 2048];

    for (int idx = threadIdx.x * 8; idx < KK * 2048; idx += 2048)
        *(bf16x8*)&sB[idx] = *(const bf16x8*)&wt[idx];   // linear coalesced
    __syncthreads();

    const int lane = threadIdx.x & 63;
    const int wv   = threadIdx.x >> 6;
    const int row0 = blockIdx.x * 64 + wv * 16;
    const int g4   = lane >> 4;
    const int r16  = lane & 15;

    int arow = row0 + r16;
    int arow_c = arow < N_NODES ? arow : 0;

    f32x4 acc[4] = {{0,0,0,0},{0,0,0,0},{0,0,0,0},{0,0,0,0}};

#pragma unroll
    for (int kk = 0; kk < KK; ++kk) {
        bf16x8 a;
        if (ABF16) {
            a = *(const bf16x8*)((const u16*)A + (size_t)arow_c * KDIM + kk * 32 + g4 * 8);
        } else {
            const float* ap = (const float*)A + (size_t)arow_c * KDIM + kk * 32 + g4 * 8;
            float4 f0 = *(const float4*)ap;
            float4 f1 = *(const float4*)(ap + 4);
            a[0] = (short)f2bf(f0.x); a[1] = (short)f2bf(f0.y);
            a[2] = (short)f2bf(f0.z); a[3] = (short)f2bf(f0.w);
            a[4] = (short)f2bf(f1.x); a[5] = (short)f2bf(f1.y);
            a[6] = (short)f2bf(f1.z); a[7] = (short)f2bf(f1.w);
        }
#pragma unroll
        for (int t = 0; t < 4; ++t) {
            bf16x8 b = *(const bf16x8*)&sB[((kk * 4 + t) * 64 + lane) * 8];
            acc[t] = __builtin_amdgcn_mfma_f32_16x16x32_bf16(a, b, acc[t], 0, 0, 0);
        }
    }

#pragma unroll
    for (int r = 0; r < 4; ++r) {
        int row = row0 + g4 * 4 + r;
        if (row < N_NODES) {
            float dinv = rsqrtf((float)(cnt[row] + 1));
#pragma unroll
            for (int t = 0; t < 4; ++t)
                G[(size_t)row * 64 + t * 16 + r16] = f2bf(acc[t][r] * dinv);
        }
    }
}

// ---- Hout(bf16) = relu(dinv[i]*(g[i] + sum_{e:dst=i} g[src_e]) + bias) ----
__global__ __launch_bounds__(256) void k_agg(const u16* __restrict__ G,
                                             const int* __restrict__ col,
                                             const int* __restrict__ cnt,
                                             const int* __restrict__ ovfc,
                                             const int* __restrict__ ovf,
                                             const float* __restrict__ bias,
                                             u16* __restrict__ Hout) {
    int node = blockIdx.x * 4 + (threadIdx.x >> 6);   // grid exact: N/4
    int lane = threadIdx.x & 63;

    int deg = cnt[node];
    int m = min(deg, WB);
    int mycol = (lane < WB) ? col[(size_t)node * WB + lane] : 0;

    float acc = bf2f(G[(size_t)node * 64 + lane]);    // self loop

    int e = 0;
    for (; e + 4 <= m; e += 4) {
        int c0 = __shfl(mycol, e + 0), c1 = __shfl(mycol, e + 1);
        int c2 = __shfl(mycol, e + 2), c3 = __shfl(mycol, e + 3);
        float v0 = bf2f(G[(size_t)c0 * 64 + lane]);
        float v1 = bf2f(G[(size_t)c1 * 64 + lane]);
        float v2 = bf2f(G[(size_t)c2 * 64 + lane]);
        float v3 = bf2f(G[(size_t)c3 * 64 + lane]);
        acc += v0; acc += v1; acc += v2; acc += v3;
    }
    for (; e < m; ++e) {
        int c = __shfl(mycol, e);
        acc += bf2f(G[(size_t)c * 64 + lane]);
    }

    int no = *ovfc;
    if (no > 0) {                        // ~never taken (deg > 48)
        no = min(no, OVF_CAP);
        for (int j = 0; j < no; ++j)
            if (ovf[2 * j + 1] == node)
                acc += bf2f(G[(size_t)ovf[2 * j] * 64 + lane]);
    }

    float dinv = rsqrtf((float)(deg + 1));
    float v = fmaxf(acc * dinv + bias[lane], 0.f);
    Hout[(size_t)node * 64 + lane] = f2bf(v);
}

// ---- z = relu(H@Wp+bp) -> out f32 [Z_OFF..]; logits = z@Wc+bc -> out f32 ----
__global__ __launch_bounds__(256) void k_mlp(const u16* __restrict__ H,
                                             const u16* __restrict__ wt,
                                             const float* __restrict__ bp,
                                             const float* __restrict__ bc,
                                             float* __restrict__ out) {
    __shared__ __align__(16) u16 sP[2 * 2048];
    __shared__ __align__(16) u16 sC[1024];
    __shared__ __align__(16) u16 zt[4][16][72];

    for (int idx = threadIdx.x * 8; idx < 4096; idx += 2048)
        *(bf16x8*)&sP[idx] = *(const bf16x8*)&wt[WT_WP + idx];
    {
        int idx = threadIdx.x * 8;
        if (idx < 1024)
            *(bf16x8*)&sC[idx] = *(const bf16x8*)&wt[WT_WC + idx];
    }
    __syncthreads();

    const int lane = threadIdx.x & 63;
    const int wv   = threadIdx.x >> 6;
    const int row0 = blockIdx.x * 64 + wv * 16;
    const int g4   = lane >> 4;
    const int r16  = lane & 15;

    int arow = row0 + r16;
    int arow_c = arow < N_NODES ? arow : (N_NODES - 1);

    f32x4 zac[4] = {{0,0,0,0},{0,0,0,0},{0,0,0,0},{0,0,0,0}};
#pragma unroll
    for (int kk = 0; kk < 2; ++kk) {
        bf16x8 a = *(const bf16x8*)((const u16*)H + (size_t)arow_c * 64 + kk * 32 + g4 * 8);
#pragma unroll
        for (int t = 0; t < 4; ++t) {
            bf16x8 b = *(const bf16x8*)&sP[((kk * 4 + t) * 64 + lane) * 8];
            zac[t] = __builtin_amdgcn_mfma_f32_16x16x32_bf16(a, b, zac[t], 0, 0, 0);
        }
    }

#pragma unroll
    for (int r = 0; r < 4; ++r) {
        int row = row0 + g4 * 4 + r;
#pragma unroll
        for (int t = 0; t < 4; ++t) {
            float v = zac[t][r] + bp[t * 16 + r16];
            v = fmaxf(v, 0.f);
            zt[wv][g4 * 4 + r][t * 16 + r16] = f2bf(v);
            if (row < N_NODES)
                out[(size_t)Z_OFF + (size_t)row * 64 + t * 16 + r16] = v;
        }
    }
    __syncthreads();

    f32x4 lac = {0, 0, 0, 0};
#pragma unroll
    for (int kk = 0; kk < 2; ++kk) {
        bf16x8 a = *(const bf16x8*)&zt[wv][r16][kk * 32 + g4 * 8];
        bf16x8 b = *(const bf16x8*)&sC[(kk * 64 + lane) * 8];
        lac = __builtin_amdgcn_mfma_f32_16x16x32_bf16(a, b, lac, 0, 0, 0);
    }
#pragma unroll
    for (int r = 0; r < 4; ++r) {
        int row = row0 + g4 * 4 + r;
        if (row < N_NODES && r16 < NCLS)
            out[(size_t)row * NCLS + r16] = lac[r] + bc[r16];
    }
}

extern "C" void kernel_launch(void* const* d_in, const int* in_sizes, int n_in,
                              void* d_out, int out_size, void* d_ws, size_t ws_size,
                              hipStream_t stream) {
    const float* x  = (const float*)d_in[0];
    const int*   ei = (const int*)d_in[1];
    const float* W1 = (const float*)d_in[2];
    const float* b1 = (const float*)d_in[3];
    const float* W2 = (const float*)d_in[4];
    const float* b2 = (const float*)d_in[5];
    const float* Wp = (const float*)d_in[6];
    const float* bp = (const float*)d_in[7];
    const float* Wc = (const float*)d_in[8];
    const float* bc = (const float*)d_in[9];
    float* out = (float*)d_out;

    char* ws   = (char*)d_ws;
    int*  cnt  = (int*)(ws + OFF_CNT);
    int*  ovfc = (int*)(ws + OFF_OVFC);
    int*  ovf  = (int*)(ws + OFF_OVF);
    int*  col  = (int*)(ws + OFF_COL);
    u16*  wt   = (u16*)(ws + OFF_WT);
    u16*  g    = (u16*)(ws + OFF_G);
    u16*  h    = (u16*)(ws + OFF_H);

    const int GB = (N_NODES + 63) / 64;   // 1563

    (void)hipMemsetAsync(ws, 0, OFF_OVF, stream);      // cnt + ovfc
    k_wprep<<<WT_TOT / 256, 256, 0, stream>>>(W1, W2, Wp, Wc, wt);
    k_fill<<<(NE / 512) * NPART, 256, 0, stream>>>(ei, cnt, col, ovfc, ovf);
    k_gemm<IN_CH, false><<<GB, 256, 0, stream>>>(x, wt + WT_W1, cnt, g);
    k_agg<<<N_NODES / 4, 256, 0, stream>>>(g, col, cnt, ovfc, ovf, b1, h);
    k_gemm<HID_D, true><<<GB, 256, 0, stream>>>(h, wt + WT_W2, cnt, g);
    k_agg<<<N_NODES / 4, 256, 0, stream>>>(g, col, cnt, ovfc, ovf, b2, h);
    k_mlp<<<GB, 256, 0, stream>>>(h, wt, bp, bc, out);
}